// Round 5
// baseline (321.417 us; speedup 1.0000x reference)
//
#include <hip/hip_runtime.h>

typedef __attribute__((ext_vector_type(8))) short short8;
typedef __attribute__((ext_vector_type(4))) float f32x4;
typedef unsigned short u16;
typedef unsigned int u32;

#define NH 16

#if __has_builtin(__builtin_amdgcn_exp2f)
#define EXP2(x) __builtin_amdgcn_exp2f(x)
#else
#define EXP2(x) exp2f(x)
#endif

__device__ __forceinline__ u32 f2bf(float f) {
  u32 u = __builtin_bit_cast(u32, f);
  return (u + 0x7fffu + ((u >> 16) & 1u)) >> 16;  // round-nearest-even bf16 bits
}

// async global->LDS, 16B per lane. LDS dest is wave-uniform base + lane*16.
__device__ __forceinline__ void gload_lds16(const u16* g, u16* l) {
  __builtin_amdgcn_global_load_lds(
      (const __attribute__((address_space(1))) void*)g,
      (__attribute__((address_space(3))) void*)l, 16, 0, 0);
}

// ---------- convert x + Wq,Wk,Wv,Wo (fp32) -> bf16 into ws ----------
__global__ __launch_bounds__(256) void k_convert(
    const float* __restrict__ x, const float* __restrict__ wq,
    const float* __restrict__ wk, const float* __restrict__ wv,
    const float* __restrict__ wo, u16* __restrict__ dst) {
  int i = blockIdx.x * 256 + threadIdx.x;
  size_t e = (size_t)i * 4;
  const float* s; size_t off;
  if (e < 8388608ull)       { s = x;  off = e; }
  else if (e < 9437184ull)  { s = wq; off = e - 8388608ull; }
  else if (e < 10485760ull) { s = wk; off = e - 9437184ull; }
  else if (e < 11534336ull) { s = wv; off = e - 10485760ull; }
  else                      { s = wo; off = e - 11534336ull; }
  float4 d = *(const float4*)(s + off);
  ushort4 o;
  o.x = (u16)f2bf(d.x); o.y = (u16)f2bf(d.y);
  o.z = (u16)f2bf(d.z); o.w = (u16)f2bf(d.w);
  *(ushort4*)(dst + e) = o;
}

// ---------- 256x256 8-phase GEMM core: C[256x256] = A[256xK] * B[256xK]^T --
// Port of the learn_hip m201 template: 512 threads = 8 waves (2M x 4N),
// BK=64, true dbuf (128 KB LDS), gload_lds16 staging with the R1-verified
// constant-per-lane granule XOR swizzle (LDS[row][g] = global g^(row&7)),
// all 8 staging loads issued at K-tile top (hidden across 4 phases, drained
// once per K-tile by __syncthreads), 4 quadrant-phases x 16 MFMA with raw
// s_barrier pairs + setprio(1) + sched_barrier(0) phase pinning.
// Requires m0/n0 already defined. Defines tid/wave/lane/quad/l16/wr/wn/acc.
#define GEMM256_CORE(Aptr, Bptr)                                               \
  __shared__ u16 As[2][16384];                                                 \
  __shared__ u16 Bs[2][16384];                                                 \
  const int tid = threadIdx.x;                                                 \
  const int wave = tid >> 6, lane = tid & 63;                                  \
  const int quad = lane >> 4, l16 = lane & 15;                                 \
  const int wr = wave >> 2, wn = wave & 3;                                     \
  const int swz = l16 & 7;                                                     \
  const int srow = tid >> 3;                                                   \
  const int srcg = (tid & 7) ^ (srow & 7);                                     \
  const u16* aTh = Aptr + (size_t)(m0 + srow) * 1024 + srcg * 8;               \
  const u16* bTh = Bptr + (size_t)(n0 + srow) * 1024 + srcg * 8;               \
  u16* aDst = &As[0][0] + wave * 512;                                          \
  u16* bDst = &Bs[0][0] + wave * 512;                                          \
  f32x4 acc[8][4];                                                             \
  {                                                                            \
    f32x4 z = {0.f, 0.f, 0.f, 0.f};                                            \
    for (int a = 0; a < 8; ++a) for (int b2 = 0; b2 < 4; ++b2) acc[a][b2] = z; \
  }                                                                            \
  _Pragma("unroll")                                                            \
  for (int j = 0; j < 4; ++j) {                                                \
    gload_lds16(aTh + j * 65536, aDst + j * 4096);                             \
    gload_lds16(bTh + j * 65536, bDst + j * 4096);                             \
  }                                                                            \
  __syncthreads();                                                             \
  for (int t = 0; t < 16; ++t) {                                               \
    const int p = t & 1;                                                       \
    if (t < 15) {                                                              \
      const u16* aT = aTh + (t + 1) * 64;                                      \
      const u16* bT = bTh + (t + 1) * 64;                                      \
      u16* aD = aDst + (p ^ 1) * 16384;                                        \
      u16* bD = bDst + (p ^ 1) * 16384;                                        \
      _Pragma("unroll")                                                        \
      for (int j = 0; j < 4; ++j) {                                            \
        gload_lds16(aT + j * 65536, aD + j * 4096);                            \
        gload_lds16(bT + j * 65536, bD + j * 4096);                            \
      }                                                                        \
    }                                                                          \
    __builtin_amdgcn_sched_barrier(0);                                         \
    const u16* Ab = &As[p][0];                                                 \
    const u16* Bb = &Bs[p][0];                                                 \
    short8 af[4][2], bfr[2][2];                                                \
    /* q0: mh0 x nh0 */                                                        \
    _Pragma("unroll")                                                          \
    for (int mt = 0; mt < 4; ++mt)                                             \
      _Pragma("unroll")                                                        \
      for (int ks = 0; ks < 2; ++ks)                                           \
        af[mt][ks] = *(const short8*)(Ab + (wr * 128 + mt * 16 + l16) * 64     \
                                         + ((ks * 4 + quad) ^ swz) * 8);       \
    _Pragma("unroll")                                                          \
    for (int nt = 0; nt < 2; ++nt)                                             \
      _Pragma("unroll")                                                        \
      for (int ks = 0; ks < 2; ++ks)                                           \
        bfr[nt][ks] = *(const short8*)(Bb + (wn * 64 + nt * 16 + l16) * 64     \
                                          + ((ks * 4 + quad) ^ swz) * 8);      \
    __builtin_amdgcn_s_barrier();                                              \
    __builtin_amdgcn_s_setprio(1);                                             \
    _Pragma("unroll")                                                          \
    for (int mt = 0; mt < 4; ++mt)                                             \
      _Pragma("unroll")                                                        \
      for (int nt = 0; nt < 2; ++nt)                                           \
        _Pragma("unroll")                                                      \
        for (int ks = 0; ks < 2; ++ks)                                         \
          acc[mt][nt] = __builtin_amdgcn_mfma_f32_16x16x32_bf16(               \
              af[mt][ks], bfr[nt][ks], acc[mt][nt], 0, 0, 0);                  \
    __builtin_amdgcn_s_setprio(0);                                             \
    __builtin_amdgcn_s_barrier();                                              \
    __builtin_amdgcn_sched_barrier(0);                                         \
    /* q1: mh0 x nh1 (af kept) */                                              \
    _Pragma("unroll")                                                          \
    for (int nt = 0; nt < 2; ++nt)                                             \
      _Pragma("unroll")                                                        \
      for (int ks = 0; ks < 2; ++ks)                                           \
        bfr[nt][ks] = *(const short8*)(Bb + (wn * 64 + (nt + 2) * 16 + l16) * 64 \
                                          + ((ks * 4 + quad) ^ swz) * 8);      \
    __builtin_amdgcn_s_barrier();                                              \
    __builtin_amdgcn_s_setprio(1);                                             \
    _Pragma("unroll")                                                          \
    for (int mt = 0; mt < 4; ++mt)                                             \
      _Pragma("unroll")                                                        \
      for (int nt = 0; nt < 2; ++nt)                                           \
        _Pragma("unroll")                                                      \
        for (int ks = 0; ks < 2; ++ks)                                         \
          acc[mt][nt + 2] = __builtin_amdgcn_mfma_f32_16x16x32_bf16(           \
              af[mt][ks], bfr[nt][ks], acc[mt][nt + 2], 0, 0, 0);              \
    __builtin_amdgcn_s_setprio(0);                                             \
    __builtin_amdgcn_s_barrier();                                              \
    __builtin_amdgcn_sched_barrier(0);                                         \
    /* q2: mh1 x nh1 (bfr kept) */                                             \
    _Pragma("unroll")                                                          \
    for (int mt = 0; mt < 4; ++mt)                                             \
      _Pragma("unroll")                                                        \
      for (int ks = 0; ks < 2; ++ks)                                           \
        af[mt][ks] = *(const short8*)(Ab + (wr * 128 + (mt + 4) * 16 + l16) * 64 \
                                         + ((ks * 4 + quad) ^ swz) * 8);       \
    __builtin_amdgcn_s_barrier();                                              \
    __builtin_amdgcn_s_setprio(1);                                             \
    _Pragma("unroll")                                                          \
    for (int mt = 0; mt < 4; ++mt)                                             \
      _Pragma("unroll")                                                        \
      for (int nt = 0; nt < 2; ++nt)                                           \
        _Pragma("unroll")                                                      \
        for (int ks = 0; ks < 2; ++ks)                                         \
          acc[mt + 4][nt + 2] = __builtin_amdgcn_mfma_f32_16x16x32_bf16(       \
              af[mt][ks], bfr[nt][ks], acc[mt + 4][nt + 2], 0, 0, 0);          \
    __builtin_amdgcn_s_setprio(0);                                             \
    __builtin_amdgcn_s_barrier();                                              \
    __builtin_amdgcn_sched_barrier(0);                                         \
    /* q3: mh1 x nh0 (re-read bfr nh0) */                                      \
    _Pragma("unroll")                                                          \
    for (int nt = 0; nt < 2; ++nt)                                             \
      _Pragma("unroll")                                                        \
      for (int ks = 0; ks < 2; ++ks)                                           \
        bfr[nt][ks] = *(const short8*)(Bb + (wn * 64 + nt * 16 + l16) * 64     \
                                          + ((ks * 4 + quad) ^ swz) * 8);      \
    __builtin_amdgcn_s_barrier();                                              \
    __builtin_amdgcn_s_setprio(1);                                             \
    _Pragma("unroll")                                                          \
    for (int mt = 0; mt < 4; ++mt)                                             \
      _Pragma("unroll")                                                        \
      for (int nt = 0; nt < 2; ++nt)                                           \
        _Pragma("unroll")                                                      \
        for (int ks = 0; ks < 2; ++ks)                                         \
          acc[mt + 4][nt] = __builtin_amdgcn_mfma_f32_16x16x32_bf16(           \
              af[mt][ks], bfr[nt][ks], acc[mt + 4][nt], 0, 0, 0);              \
    __builtin_amdgcn_s_setprio(0);                                             \
    __syncthreads(); /* drains staged vmcnt + swaps buffers */                 \
  }

// ---------- QKV projection, fused N=3072: out scattered [B,H,T,Dh] bf16 ----
__global__ __launch_bounds__(512, 2) void k_gemm_qkv(
    const u16* __restrict__ A, const u16* __restrict__ W,
    const float* __restrict__ bq, const float* __restrict__ bk,
    const float* __restrict__ bv, u16* __restrict__ qkv) {
  const int bid = blockIdx.x;                // 384 blocks
  const int sw = (bid & 7) * 48 + (bid >> 3);  // bijective XCD chunking
  const int ntile = sw % 12, mtile = sw / 12;
  const int m0 = mtile * 256, n0 = ntile * 256;
  const int z = n0 >> 10;
  const float* bias = (z == 0) ? bq : (z == 1) ? bk : bv;
  u16* out = qkv + (size_t)z * 8388608;
  // q: fold 1/sqrt(64) AND log2(e) (attention softmax runs in exp2 domain)
  const float scl = (z == 0) ? 0.125f * 1.44269504088896340736f : 1.0f;
  GEMM256_CORE(A, W)
  #pragma unroll
  for (int mt = 0; mt < 8; ++mt) {
    #pragma unroll
    for (int nt = 0; nt < 4; ++nt) {
      int n = n0 + wn * 64 + nt * 16 + l16;
      int nn = n & 1023;
      float bn = bias[nn];
      int h = nn >> 6, d = nn & 63;
      #pragma unroll
      for (int r = 0; r < 4; ++r) {
        int m = m0 + wr * 128 + mt * 16 + quad * 4 + r;
        int b = m >> 11, tt = m & 2047;
        float val = (acc[mt][nt][r] + bn) * scl;
        out[(((size_t)(b * NH + h) * 2048 + tt) << 6) + d] = (u16)f2bf(val);
      }
    }
  }
}

// ---------- output projection: fp32 out [8192][1024] ----------
__global__ __launch_bounds__(512, 2) void k_gemm_out(
    const u16* __restrict__ A, const u16* __restrict__ Bw,
    const float* __restrict__ bias, float* __restrict__ out) {
  const int bid = blockIdx.x;                // 128 blocks
  const int sw = (bid & 7) * 16 + (bid >> 3);
  const int ntile = sw % 4, mtile = sw / 4;
  const int m0 = mtile * 256, n0 = ntile * 256;
  GEMM256_CORE(A, Bw)
  #pragma unroll
  for (int mt = 0; mt < 8; ++mt) {
    #pragma unroll
    for (int nt = 0; nt < 4; ++nt) {
      int n = n0 + wn * 64 + nt * 16 + l16;
      float bn = bias[n];
      #pragma unroll
      for (int r = 0; r < 4; ++r) {
        int m = m0 + wr * 128 + mt * 16 + quad * 4 + r;
        out[(size_t)m * 1024 + n] = acc[mt][nt][r] + bn;
      }
    }
  }
}

// ---------- V transpose: [B,H,T,Dh] -> [B,H,Dh,T] bf16 ----------
__global__ __launch_bounds__(256) void k_vtrans(const u16* __restrict__ v,
                                                u16* __restrict__ vt) {
  int t0 = blockIdx.x * 64;
  int bh = blockIdx.y;
  const u16* vs = v + (size_t)bh * 2048 * 64;
  u16* vd = vt + (size_t)bh * 64 * 2048;
  int tid = threadIdx.x;
  #pragma unroll
  for (int it = 0; it < 2; ++it) {
    int c = it * 256 + tid;
    int d = c >> 3, tc = c & 7;
    u16 tmp[8];
    #pragma unroll
    for (int j = 0; j < 8; ++j)
      tmp[j] = vs[(size_t)(t0 + tc * 8 + j) * 64 + d];
    uint4 pk;
    pk.x = (u32)tmp[0] | ((u32)tmp[1] << 16);
    pk.y = (u32)tmp[2] | ((u32)tmp[3] << 16);
    pk.z = (u32)tmp[4] | ((u32)tmp[5] << 16);
    pk.w = (u32)tmp[6] | ((u32)tmp[7] << 16);
    *(uint4*)(vd + (size_t)d * 2048 + t0 + tc * 8) = pk;
  }
}

// ---------- flash attention (R4, verified 105.7us): S^T orientation,
// paired q-tiles, in-register P exchange, dbuf K/V LDS (1 barrier/step),
// same-bh-per-XCD grid for L2 K/V residency ----------
#define ATTN_SUB(P, QF0, QF1, O, MI, LI, DIAG)                                 \
  {                                                                            \
    f32x4 st[4];                                                               \
    _Pragma("unroll")                                                          \
    for (int nt = 0; nt < 4; ++nt) {                                           \
      short8 kf0 = *(const short8*)(&Ks[P][(nt * 16 + l16) * 72 + quad * 8]);  \
      short8 kf1 = *(const short8*)(&Ks[P][(nt * 16 + l16) * 72 + 32 + quad * 8]); \
      f32x4 z4 = {0.f, 0.f, 0.f, 0.f};                                         \
      z4 = __builtin_amdgcn_mfma_f32_16x16x32_bf16(kf0, QF0, z4, 0, 0, 0);     \
      st[nt] = __builtin_amdgcn_mfma_f32_16x16x32_bf16(kf1, QF1, z4, 0, 0, 0); \
    }                                                                          \
    if (DIAG) {                                                                \
      int q_loc = wave * 16 + l16;                                             \
      _Pragma("unroll")                                                        \
      for (int nt = 0; nt < 4; ++nt) {                                         \
        _Pragma("unroll")                                                      \
        for (int r = 0; r < 4; ++r) {                                          \
          int k_loc = nt * 16 + quad * 4 + r;                                  \
          if (k_loc > q_loc) st[nt][r] = -1e30f;                               \
        }                                                                      \
      }                                                                        \
    }                                                                          \
    float mq[4];                                                               \
    _Pragma("unroll")                                                          \
    for (int nt = 0; nt < 4; ++nt)                                             \
      mq[nt] = fmaxf(fmaxf(st[nt][0], st[nt][1]), fmaxf(st[nt][2], st[nt][3]));\
    float mx = fmaxf(fmaxf(mq[0], mq[1]), fmaxf(mq[2], mq[3]));                \
    mx = fmaxf(mx, __shfl_xor(mx, 16, 64));                                    \
    mx = fmaxf(mx, __shfl_xor(mx, 32, 64));                                    \
    float mnew = fmaxf(MI, mx);                                                \
    float alpha = EXP2(MI - mnew);                                             \
    MI = mnew;                                                                 \
    LI *= alpha;                                                               \
    _Pragma("unroll")                                                          \
    for (int r = 0; r < 4; ++r) {                                              \
      float av = __shfl(alpha, quad * 4 + r, 16);                              \
      _Pragma("unroll")                                                        \
      for (int dt = 0; dt < 4; ++dt) O[dt][r] *= av;                           \
    }                                                                          \
    u32 Wx[4], Wy[4];                                                          \
    float sq[4];                                                               \
    _Pragma("unroll")                                                          \
    for (int nt = 0; nt < 4; ++nt) {                                           \
      float p0 = EXP2(st[nt][0] - mnew);                                       \
      float p1 = EXP2(st[nt][1] - mnew);                                       \
      float p2 = EXP2(st[nt][2] - mnew);                                       \
      float p3 = EXP2(st[nt][3] - mnew);                                       \
      sq[nt] = (p0 + p1) + (p2 + p3);                                          \
      Wx[nt] = f2bf(p0) | (f2bf(p1) << 16);                                    \
      Wy[nt] = f2bf(p2) | (f2bf(p3) << 16);                                    \
    }                                                                          \
    float sum = (sq[0] + sq[1]) + (sq[2] + sq[3]);                             \
    sum += __shfl_xor(sum, 16, 64);                                            \
    sum += __shfl_xor(sum, 32, 64);                                            \
    LI += sum;                                                                 \
    uint4 t0, t1;                                                              \
    {                                                                          \
      u32 e, f;                                                                \
      e = __shfl(Wx[0], s0, 64); f = __shfl(Wx[1], s0, 64); t0.x = hi ? f : e; \
      e = __shfl(Wy[0], s0, 64); f = __shfl(Wy[1], s0, 64); t0.y = hi ? f : e; \
      e = __shfl(Wx[0], s1, 64); f = __shfl(Wx[1], s1, 64); t0.z = hi ? f : e; \
      e = __shfl(Wy[0], s1, 64); f = __shfl(Wy[1], s1, 64); t0.w = hi ? f : e; \
      e = __shfl(Wx[2], s0, 64); f = __shfl(Wx[3], s0, 64); t1.x = hi ? f : e; \
      e = __shfl(Wy[2], s0, 64); f = __shfl(Wy[3], s0, 64); t1.y = hi ? f : e; \
      e = __shfl(Wx[2], s1, 64); f = __shfl(Wx[3], s1, 64); t1.z = hi ? f : e; \
      e = __shfl(Wy[2], s1, 64); f = __shfl(Wy[3], s1, 64); t1.w = hi ? f : e; \
    }                                                                          \
    short8 pf0 = __builtin_bit_cast(short8, t0);                               \
    short8 pf1 = __builtin_bit_cast(short8, t1);                               \
    _Pragma("unroll")                                                          \
    for (int dt = 0; dt < 4; ++dt) {                                           \
      short8 vf0 = *(const short8*)(&Vs[P][(dt * 16 + l16) * 72 + quad * 8]);  \
      short8 vf1 = *(const short8*)(&Vs[P][(dt * 16 + l16) * 72 + 32 + quad * 8]); \
      O[dt] = __builtin_amdgcn_mfma_f32_16x16x32_bf16(pf0, vf0, O[dt], 0, 0, 0); \
      O[dt] = __builtin_amdgcn_mfma_f32_16x16x32_bf16(pf1, vf1, O[dt], 0, 0, 0); \
    }                                                                          \
  }

#define ATTN_EPI(O, LI, QT)                                                    \
  _Pragma("unroll")                                                            \
  for (int r = 0; r < 4; ++r) {                                                \
    float lv = __shfl(LI, quad * 4 + r, 16);                                   \
    float inv = 1.0f / lv;                                                     \
    int t = (QT) * 64 + wave * 16 + quad * 4 + r;                              \
    _Pragma("unroll")                                                          \
    for (int dt = 0; dt < 4; ++dt) {                                           \
      int d = dt * 16 + l16;                                                   \
      y[(((size_t)b * 2048 + t) * NH + h) * 64 + d] = (u16)f2bf(O[dt][r] * inv); \
    }                                                                          \
  }

__global__ __launch_bounds__(256, 4) void k_attn(
    const u16* __restrict__ q, const u16* __restrict__ k,
    const u16* __restrict__ vt, u16* __restrict__ y) {
  const int tid = threadIdx.x;
  const int wave = tid >> 6, lane = tid & 63;
  const int quad = lane >> 4, l16 = lane & 15;
  const int bh = blockIdx.x, bx = blockIdx.y;  // grid (64,16): id%8 = bh%8
  const int qtB = bx, qtA = 31 - bx;           // qtB in 0..15, qtA in 16..31
  const int b = bh >> 4, h = bh & 15;

  __shared__ u16 Ks[2][64 * 72];
  __shared__ u16 Vs[2][64 * 72];               // [d][kidx]

  const u16* qbA = q + ((size_t)bh * 2048 + qtA * 64 + wave * 16 + l16) * 64;
  short8 qA0 = *(const short8*)(qbA + quad * 8);
  short8 qA1 = *(const short8*)(qbA + 32 + quad * 8);
  const u16* qbB = q + ((size_t)bh * 2048 + qtB * 64 + wave * 16 + l16) * 64;
  short8 qB0 = *(const short8*)(qbB + quad * 8);
  short8 qB1 = *(const short8*)(qbB + 32 + quad * 8);

  f32x4 oA[4], oB[4];
  {
    f32x4 z = {0.f, 0.f, 0.f, 0.f};
    #pragma unroll
    for (int dt = 0; dt < 4; ++dt) { oA[dt] = z; oB[dt] = z; }
  }
  float mA = -1e30f, lA = 0.f, mB = -1e30f, lB = 0.f;

  const u16* kbase = k + (size_t)bh * 131072;
  const u16* vbase = vt + (size_t)bh * 131072;
  const int r0 = tid >> 3, cc = tid & 7;
  // P-exchange source lanes: receiver (quad,ks) pulls W[2ks+hi] words from
  // lanes s0 (j=0..3) and s1 (j=4..7)  [verified R3]
  const int s0 = ((quad & 1) << 5) + l16, s1 = s0 + 16;
  const int hi = quad >> 1;

  // prologue: stage kt=0 into buffer 0
  {
    uint4 k0 = *(const uint4*)(kbase + (size_t)r0 * 64 + cc * 8);
    uint4 k1 = *(const uint4*)(kbase + (size_t)(r0 + 32) * 64 + cc * 8);
    uint4 v0 = *(const uint4*)(vbase + (size_t)r0 * 2048 + cc * 8);
    uint4 v1 = *(const uint4*)(vbase + (size_t)(r0 + 32) * 2048 + cc * 8);
    *(uint4*)(&Ks[0][r0 * 72 + cc * 8]) = k0;
    *(uint4*)(&Ks[0][(r0 + 32) * 72 + cc * 8]) = k1;
    *(uint4*)(&Vs[0][r0 * 72 + cc * 8]) = v0;
    *(uint4*)(&Vs[0][(r0 + 32) * 72 + cc * 8]) = v1;
  }
  __syncthreads();

  for (int kt = 0; kt <= qtA; ++kt) {
    const int p = kt & 1;
    const bool pre = (kt < qtA);
    uint4 kr0, kr1, vr0, vr1;
    if (pre) {  // issue next-tile loads early; consumed after compute
      const u16* kb = kbase + (size_t)(kt + 1) * 4096;
      const u16* vb = vbase + (kt + 1) * 64;
      kr0 = *(const uint4*)(kb + (size_t)r0 * 64 + cc * 8);
      kr1 = *(const uint4*)(kb + (size_t)(r0 + 32) * 64 + cc * 8);
      vr0 = *(const uint4*)(vb + (size_t)r0 * 2048 + cc * 8);
      vr1 = *(const uint4*)(vb + (size_t)(r0 + 32) * 2048 + cc * 8);
    }

    ATTN_SUB(p, qA0, qA1, oA, mA, lA, (kt == qtA))
    if (kt <= qtB) {
      ATTN_SUB(p, qB0, qB1, oB, mB, lB, (kt == qtB))
    }

    if (pre) {  // write next tile into the other buffer
      *(uint4*)(&Ks[p ^ 1][r0 * 72 + cc * 8]) = kr0;
      *(uint4*)(&Ks[p ^ 1][(r0 + 32) * 72 + cc * 8]) = kr1;
      *(uint4*)(&Vs[p ^ 1][r0 * 72 + cc * 8]) = vr0;
      *(uint4*)(&Vs[p ^ 1][(r0 + 32) * 72 + cc * 8]) = vr1;
    }
    __syncthreads();  // single barrier: orders buf[p^1] writes + buf[p] reads
  }

  ATTN_EPI(oA, lA, qtA)
  ATTN_EPI(oB, lB, qtB)
}

extern "C" void kernel_launch(void* const* d_in, const int* in_sizes, int n_in,
                              void* d_out, int out_size, void* d_ws, size_t ws_size,
                              hipStream_t stream) {
  const float* x  = (const float*)d_in[0];
  const float* Wq = (const float*)d_in[1];
  const float* bq = (const float*)d_in[2];
  const float* Wk = (const float*)d_in[3];
  const float* bk = (const float*)d_in[4];
  const float* Wv = (const float*)d_in[5];
  const float* bv = (const float*)d_in[6];
  const float* Wo = (const float*)d_in[7];
  const float* bo = (const float*)d_in[8];
  float* out = (float*)d_out;

  u16* ws  = (u16*)d_ws;
  u16* xb  = ws;                   // 8388608   x bf16 [8192][1024]
  u16* Wb  = ws + 8388608;         // 4x1048576 Wq|Wk|Wv|Wo bf16
  u16* qkv = ws + 12582912;        // 3x8388608 q|k|v [B,H,T,Dh] bf16
  u16* vt  = ws + 37748736;        // 8388608   v^T [B,H,Dh,T] bf16
  u16* y   = ws + 46137344;        // 8388608   attn out [B,T,H,Dh] bf16

  k_convert<<<dim3(12288), dim3(256), 0, stream>>>(x, Wq, Wk, Wv, Wo, ws);
  k_gemm_qkv<<<dim3(384), dim3(512), 0, stream>>>(xb, Wb, bq, bk, bv, qkv);
  k_vtrans<<<dim3(32, 64), dim3(256), 0, stream>>>(qkv + 2 * 8388608, vt);
  k_attn<<<dim3(64, 16), dim3(256), 0, stream>>>(qkv, qkv + 8388608, vt, y);
  k_gemm_out<<<dim3(128), dim3(512), 0, stream>>>(y, Wb + 3 * 1048576, bo, out);
}

// Round 6
// 301.556 us; speedup vs baseline: 1.0659x; 1.0659x over previous
//
#include <hip/hip_runtime.h>

typedef __attribute__((ext_vector_type(8))) short short8;
typedef __attribute__((ext_vector_type(4))) float f32x4;
typedef unsigned short u16;
typedef unsigned int u32;

#define NH 16

#if __has_builtin(__builtin_amdgcn_exp2f)
#define EXP2(x) __builtin_amdgcn_exp2f(x)
#else
#define EXP2(x) exp2f(x)
#endif

__device__ __forceinline__ u32 f2bf(float f) {
  u32 u = __builtin_bit_cast(u32, f);
  return (u + 0x7fffu + ((u >> 16) & 1u)) >> 16;  // round-nearest-even bf16 bits
}

// async global->LDS, 16B per lane. LDS dest is wave-uniform base + lane*16.
__device__ __forceinline__ void gload_lds16(const u16* g, u16* l) {
  __builtin_amdgcn_global_load_lds(
      (const __attribute__((address_space(1))) void*)g,
      (__attribute__((address_space(3))) void*)l, 16, 0, 0);
}

// ---------- convert x + Wq,Wk,Wv,Wo (fp32) -> bf16 into ws ----------
__global__ __launch_bounds__(256) void k_convert(
    const float* __restrict__ x, const float* __restrict__ wq,
    const float* __restrict__ wk, const float* __restrict__ wv,
    const float* __restrict__ wo, u16* __restrict__ dst) {
  int i = blockIdx.x * 256 + threadIdx.x;
  size_t e = (size_t)i * 4;
  const float* s; size_t off;
  if (e < 8388608ull)       { s = x;  off = e; }
  else if (e < 9437184ull)  { s = wq; off = e - 8388608ull; }
  else if (e < 10485760ull) { s = wk; off = e - 9437184ull; }
  else if (e < 11534336ull) { s = wv; off = e - 10485760ull; }
  else                      { s = wo; off = e - 11534336ull; }
  float4 d = *(const float4*)(s + off);
  ushort4 o;
  o.x = (u16)f2bf(d.x); o.y = (u16)f2bf(d.y);
  o.z = (u16)f2bf(d.z); o.w = (u16)f2bf(d.w);
  *(ushort4*)(dst + e) = o;
}

// ---------- parameterized 8-wave GEMM core (T3+T4): C = A * B^T ----------
// 512 threads = 8 waves (2M x 4N). BM = MT*32, BN = NT*64, BK = 64, K=1024.
// True dbuf LDS. Staging via gload_lds16 with the constant-per-lane granule
// XOR swizzle (store col g^(row&7); read col (ks*4+quad)^(l16&7)).
// T4 COUNTED VMCNT: the main loop NEVER drains vmcnt to 0 — after issuing
// tile t+1's NLD loads, s_waitcnt vmcnt(NLD) waits only tile t's loads;
// t+1's stay in flight across all 4 MFMA phases. Raw s_barrier only
// (no __syncthreads -> no compiler-forced drain; the R5 drain0 regression).
// Barrier proof: q3's trailing barrier orders "all reads of buf p done"
// before iter t+1 issues gload_lds into buf p; the top-of-iter barrier
// (after per-wave vmcnt) makes tile-t data visible block-wide.
#define GPHASE(MH, NH_, LA, LB)                                                \
  if (LA) {                                                                    \
    _Pragma("unroll")                                                          \
    for (int mt = 0; mt < 4; ++mt)                                             \
      _Pragma("unroll")                                                        \
      for (int ks = 0; ks < 2; ++ks)                                           \
        af[mt][ks] = *(const short8*)(Ab +                                     \
            (wr * MT * 16 + ((MH) * 4 + mt) * 16 + l16) * 64 +                 \
            ((ks * 4 + quad) ^ swz) * 8);                                      \
  }                                                                            \
  if (LB) {                                                                    \
    _Pragma("unroll")                                                          \
    for (int nt = 0; nt < NH2; ++nt)                                           \
      _Pragma("unroll")                                                        \
      for (int ks = 0; ks < 2; ++ks)                                           \
        bfr[nt][ks] = *(const short8*)(Bb +                                    \
            (wn * NT * 16 + ((NH_) * NH2 + nt) * 16 + l16) * 64 +              \
            ((ks * 4 + quad) ^ swz) * 8);                                      \
  }                                                                            \
  __builtin_amdgcn_s_barrier();                                                \
  __builtin_amdgcn_s_setprio(1);                                               \
  _Pragma("unroll")                                                            \
  for (int mt = 0; mt < 4; ++mt)                                               \
    _Pragma("unroll")                                                          \
    for (int nt = 0; nt < NH2; ++nt)                                           \
      _Pragma("unroll")                                                        \
      for (int ks = 0; ks < 2; ++ks)                                           \
        acc[(MH) * 4 + mt][(NH_) * NH2 + nt] =                                 \
            __builtin_amdgcn_mfma_f32_16x16x32_bf16(                           \
                af[mt][ks], bfr[nt][ks], acc[(MH) * 4 + mt][(NH_) * NH2 + nt], \
                0, 0, 0);                                                      \
  __builtin_amdgcn_s_setprio(0);                                               \
  __builtin_amdgcn_s_barrier();                                                \
  __builtin_amdgcn_sched_barrier(0);

#define STAGE_T(T, PB)                                                         \
  {                                                                            \
    const u16* aT = aTh + (T) * 64;                                            \
    const u16* bT = bTh + (T) * 64;                                            \
    u16* aD = &As[PB][0] + dbase;                                              \
    u16* bD = &Bs[PB][0] + dbase;                                              \
    _Pragma("unroll")                                                          \
    for (int j = 0; j < NLA; ++j) gload_lds16(aT + j * 65536, aD + j * 4096);  \
    _Pragma("unroll")                                                          \
    for (int j = 0; j < NLB; ++j) gload_lds16(bT + j * 65536, bD + j * 4096);  \
  }

template <int MT, int NT>
__device__ __forceinline__ void gemm_core(const u16* __restrict__ Aptr,
                                          const u16* __restrict__ Bptr,
                                          int m0, int n0, f32x4 (&acc)[8][4]) {
  constexpr int NLA = MT / 2;   // A gload_lds per thread per K-tile
  constexpr int NLB = NT;       // B gload_lds per thread per K-tile
  constexpr int NLD = NLA + NLB;
  constexpr int NH2 = NT / 2;
  __shared__ u16 As[2][MT * 32 * 64];
  __shared__ u16 Bs[2][NT * 64 * 64];
  const int tid = threadIdx.x;
  const int wave = tid >> 6, lane = tid & 63;
  const int quad = lane >> 4, l16 = lane & 15;
  const int wr = wave >> 2, wn = wave & 3;
  const int swz = l16 & 7;
  const int srow = tid >> 3;
  const int srcg = (tid & 7) ^ (srow & 7);
  const u16* aTh = Aptr + (size_t)(m0 + srow) * 1024 + srcg * 8;
  const u16* bTh = Bptr + (size_t)(n0 + srow) * 1024 + srcg * 8;
  const int dbase = wave * 512;

  {
    f32x4 z = {0.f, 0.f, 0.f, 0.f};
    #pragma unroll
    for (int a = 0; a < 8; ++a)
      #pragma unroll
      for (int b2 = 0; b2 < 4; ++b2) acc[a][b2] = z;
  }

  STAGE_T(0, 0)

  short8 af[4][2], bfr[NH2][2];
  for (int t = 0; t < 16; ++t) {
    const int p = t & 1;
    if (t < 15) {
      STAGE_T(t + 1, p ^ 1)
      if constexpr (NLD == 8)
        asm volatile("s_waitcnt vmcnt(8)" ::: "memory");
      else if constexpr (NLD == 6)
        asm volatile("s_waitcnt vmcnt(6)" ::: "memory");
      else
        asm volatile("s_waitcnt vmcnt(0)" ::: "memory");
    } else {
      asm volatile("s_waitcnt vmcnt(0)" ::: "memory");
    }
    __builtin_amdgcn_s_barrier();
    __builtin_amdgcn_sched_barrier(0);
    const u16* Ab = &As[p][0];
    const u16* Bb = &Bs[p][0];
    GPHASE(0, 0, true, true)
    GPHASE(0, 1, false, true)
    GPHASE(1, 1, true, false)
    GPHASE(1, 0, false, true)
  }
}

// ---------- QKV projection, fused N=3072; V written directly transposed ----
__global__ __launch_bounds__(512, 2) void k_gemm_qkv(
    const u16* __restrict__ A, const u16* __restrict__ W,
    const float* __restrict__ bq, const float* __restrict__ bk,
    const float* __restrict__ bv, u16* __restrict__ qkv,
    u16* __restrict__ vt) {
  const int bid = blockIdx.x;                  // 384 blocks
  const int sw = (bid & 7) * 48 + (bid >> 3);  // bijective XCD chunking
  const int ntile = sw % 12, mtile = sw / 12;
  const int m0 = mtile * 256, n0 = ntile * 256;
  const int z = n0 >> 10;
  const float* bias = (z == 0) ? bq : (z == 1) ? bk : bv;
  u16* out = qkv + (size_t)z * 8388608;
  // q: fold 1/sqrt(64) AND log2(e) (attention softmax runs in exp2 domain)
  const float scl = (z == 0) ? 0.125f * 1.44269504088896340736f : 1.0f;
  f32x4 acc[8][4];
  gemm_core<8, 4>(A, W, m0, n0, acc);
  const int tid = threadIdx.x;
  const int wave = tid >> 6, lane = tid & 63;
  const int quad = lane >> 4, l16 = lane & 15;
  const int wr = wave >> 2, wn = wave & 3;
  if (z == 2) {
    // V -> vt [B,H,Dh,T] directly; r-loop spans 4 consecutive t -> uint2
    #pragma unroll
    for (int mt = 0; mt < 8; ++mt) {
      #pragma unroll
      for (int nt = 0; nt < 4; ++nt) {
        int nn = (n0 + wn * 64 + nt * 16 + l16) & 1023;
        float bn = bias[nn];
        int h = nn >> 6, d = nn & 63;
        int mbase = m0 + wr * 128 + mt * 16 + quad * 4;
        int b = mbase >> 11, tb = mbase & 2047;
        uint2 pk;
        pk.x = f2bf(acc[mt][nt][0] + bn) | (f2bf(acc[mt][nt][1] + bn) << 16);
        pk.y = f2bf(acc[mt][nt][2] + bn) | (f2bf(acc[mt][nt][3] + bn) << 16);
        *(uint2*)(vt + ((size_t)(b * NH + h) * 64 + d) * 2048 + tb) = pk;
      }
    }
  } else {
    #pragma unroll
    for (int mt = 0; mt < 8; ++mt) {
      #pragma unroll
      for (int nt = 0; nt < 4; ++nt) {
        int nn = (n0 + wn * 64 + nt * 16 + l16) & 1023;
        float bn = bias[nn];
        int h = nn >> 6, d = nn & 63;
        #pragma unroll
        for (int r = 0; r < 4; ++r) {
          int m = m0 + wr * 128 + mt * 16 + quad * 4 + r;
          int b = m >> 11, tt = m & 2047;
          float val = (acc[mt][nt][r] + bn) * scl;
          out[(((size_t)(b * NH + h) * 2048 + tt) << 6) + d] = (u16)f2bf(val);
        }
      }
    }
  }
}

// ---------- output projection: 256x128 tiles -> 256 blocks = 1/CU ----------
__global__ __launch_bounds__(512, 2) void k_gemm_out(
    const u16* __restrict__ A, const u16* __restrict__ Bw,
    const float* __restrict__ bias, float* __restrict__ out) {
  const int bid = blockIdx.x;                 // 256 blocks
  const int sw = (bid & 7) * 32 + (bid >> 3); // XCD chunking: same mtile/XCD
  const int mtile = sw >> 3, ntile = sw & 7;
  const int m0 = mtile * 256, n0 = ntile * 128;
  f32x4 acc[8][4];
  gemm_core<8, 2>(A, Bw, m0, n0, acc);
  const int tid = threadIdx.x;
  const int wave = tid >> 6, lane = tid & 63;
  const int quad = lane >> 4, l16 = lane & 15;
  const int wr = wave >> 2, wn = wave & 3;
  #pragma unroll
  for (int mt = 0; mt < 8; ++mt) {
    #pragma unroll
    for (int nt = 0; nt < 2; ++nt) {
      int n = n0 + wn * 32 + nt * 16 + l16;
      float bn = bias[n];
      #pragma unroll
      for (int r = 0; r < 4; ++r) {
        int m = m0 + wr * 128 + mt * 16 + quad * 4 + r;
        out[(size_t)m * 1024 + n] = acc[mt][nt][r] + bn;
      }
    }
  }
}

// ---------- flash attention (R4-verified, ~100-106us): S^T orientation,
// paired q-tiles, in-register P exchange, dbuf K/V LDS (1 barrier/step),
// same-bh-per-XCD grid for L2 K/V residency ----------
#define ATTN_SUB(P, QF0, QF1, O, MI, LI, DIAG)                                 \
  {                                                                            \
    f32x4 st[4];                                                               \
    _Pragma("unroll")                                                          \
    for (int nt = 0; nt < 4; ++nt) {                                           \
      short8 kf0 = *(const short8*)(&Ks[P][(nt * 16 + l16) * 72 + quad * 8]);  \
      short8 kf1 = *(const short8*)(&Ks[P][(nt * 16 + l16) * 72 + 32 + quad * 8]); \
      f32x4 z4 = {0.f, 0.f, 0.f, 0.f};                                         \
      z4 = __builtin_amdgcn_mfma_f32_16x16x32_bf16(kf0, QF0, z4, 0, 0, 0);     \
      st[nt] = __builtin_amdgcn_mfma_f32_16x16x32_bf16(kf1, QF1, z4, 0, 0, 0); \
    }                                                                          \
    if (DIAG) {                                                                \
      int q_loc = wave * 16 + l16;                                             \
      _Pragma("unroll")                                                        \
      for (int nt = 0; nt < 4; ++nt) {                                         \
        _Pragma("unroll")                                                      \
        for (int r = 0; r < 4; ++r) {                                          \
          int k_loc = nt * 16 + quad * 4 + r;                                  \
          if (k_loc > q_loc) st[nt][r] = -1e30f;                               \
        }                                                                      \
      }                                                                        \
    }                                                                          \
    float mq[4];                                                               \
    _Pragma("unroll")                                                          \
    for (int nt = 0; nt < 4; ++nt)                                             \
      mq[nt] = fmaxf(fmaxf(st[nt][0], st[nt][1]), fmaxf(st[nt][2], st[nt][3]));\
    float mx = fmaxf(fmaxf(mq[0], mq[1]), fmaxf(mq[2], mq[3]));                \
    mx = fmaxf(mx, __shfl_xor(mx, 16, 64));                                    \
    mx = fmaxf(mx, __shfl_xor(mx, 32, 64));                                    \
    float mnew = fmaxf(MI, mx);                                                \
    float alpha = EXP2(MI - mnew);                                             \
    MI = mnew;                                                                 \
    LI *= alpha;                                                               \
    _Pragma("unroll")                                                          \
    for (int r = 0; r < 4; ++r) {                                              \
      float av = __shfl(alpha, quad * 4 + r, 16);                              \
      _Pragma("unroll")                                                        \
      for (int dt = 0; dt < 4; ++dt) O[dt][r] *= av;                           \
    }                                                                          \
    u32 Wx[4], Wy[4];                                                          \
    float sq[4];                                                               \
    _Pragma("unroll")                                                          \
    for (int nt = 0; nt < 4; ++nt) {                                           \
      float p0 = EXP2(st[nt][0] - mnew);                                       \
      float p1 = EXP2(st[nt][1] - mnew);                                       \
      float p2 = EXP2(st[nt][2] - mnew);                                       \
      float p3 = EXP2(st[nt][3] - mnew);                                       \
      sq[nt] = (p0 + p1) + (p2 + p3);                                          \
      Wx[nt] = f2bf(p0) | (f2bf(p1) << 16);                                    \
      Wy[nt] = f2bf(p2) | (f2bf(p3) << 16);                                    \
    }                                                                          \
    float sum = (sq[0] + sq[1]) + (sq[2] + sq[3]);                             \
    sum += __shfl_xor(sum, 16, 64);                                            \
    sum += __shfl_xor(sum, 32, 64);                                            \
    LI += sum;                                                                 \
    uint4 t0, t1;                                                              \
    {                                                                          \
      u32 e, f;                                                                \
      e = __shfl(Wx[0], s0, 64); f = __shfl(Wx[1], s0, 64); t0.x = hi ? f : e; \
      e = __shfl(Wy[0], s0, 64); f = __shfl(Wy[1], s0, 64); t0.y = hi ? f : e; \
      e = __shfl(Wx[0], s1, 64); f = __shfl(Wx[1], s1, 64); t0.z = hi ? f : e; \
      e = __shfl(Wy[0], s1, 64); f = __shfl(Wy[1], s1, 64); t0.w = hi ? f : e; \
      e = __shfl(Wx[2], s0, 64); f = __shfl(Wx[3], s0, 64); t1.x = hi ? f : e; \
      e = __shfl(Wy[2], s0, 64); f = __shfl(Wy[3], s0, 64); t1.y = hi ? f : e; \
      e = __shfl(Wx[2], s1, 64); f = __shfl(Wx[3], s1, 64); t1.z = hi ? f : e; \
      e = __shfl(Wy[2], s1, 64); f = __shfl(Wy[3], s1, 64); t1.w = hi ? f : e; \
    }                                                                          \
    short8 pf0 = __builtin_bit_cast(short8, t0);                               \
    short8 pf1 = __builtin_bit_cast(short8, t1);                               \
    _Pragma("unroll")                                                          \
    for (int dt = 0; dt < 4; ++dt) {                                           \
      short8 vf0 = *(const short8*)(&Vs[P][(dt * 16 + l16) * 72 + quad * 8]);  \
      short8 vf1 = *(const short8*)(&Vs[P][(dt * 16 + l16) * 72 + 32 + quad * 8]); \
      O[dt] = __builtin_amdgcn_mfma_f32_16x16x32_bf16(pf0, vf0, O[dt], 0, 0, 0); \
      O[dt] = __builtin_amdgcn_mfma_f32_16x16x32_bf16(pf1, vf1, O[dt], 0, 0, 0); \
    }                                                                          \
  }

#define ATTN_EPI(O, LI, QT)                                                    \
  _Pragma("unroll")                                                            \
  for (int r = 0; r < 4; ++r) {                                                \
    float lv = __shfl(LI, quad * 4 + r, 16);                                   \
    float inv = 1.0f / lv;                                                     \
    int t = (QT) * 64 + wave * 16 + quad * 4 + r;                              \
    _Pragma("unroll")                                                          \
    for (int dt = 0; dt < 4; ++dt) {                                           \
      int d = dt * 16 + l16;                                                   \
      y[(((size_t)b * 2048 + t) * NH + h) * 64 + d] = (u16)f2bf(O[dt][r] * inv); \
    }                                                                          \
  }

__global__ __launch_bounds__(256, 4) void k_attn(
    const u16* __restrict__ q, const u16* __restrict__ k,
    const u16* __restrict__ vt, u16* __restrict__ y) {
  const int tid = threadIdx.x;
  const int wave = tid >> 6, lane = tid & 63;
  const int quad = lane >> 4, l16 = lane & 15;
  const int bh = blockIdx.x, bx = blockIdx.y;  // grid (64,16): id%8 = bh%8
  const int qtB = bx, qtA = 31 - bx;           // qtB in 0..15, qtA in 16..31
  const int b = bh >> 4, h = bh & 15;

  __shared__ u16 Ks[2][64 * 72];
  __shared__ u16 Vs[2][64 * 72];               // [d][kidx]

  const u16* qbA = q + ((size_t)bh * 2048 + qtA * 64 + wave * 16 + l16) * 64;
  short8 qA0 = *(const short8*)(qbA + quad * 8);
  short8 qA1 = *(const short8*)(qbA + 32 + quad * 8);
  const u16* qbB = q + ((size_t)bh * 2048 + qtB * 64 + wave * 16 + l16) * 64;
  short8 qB0 = *(const short8*)(qbB + quad * 8);
  short8 qB1 = *(const short8*)(qbB + 32 + quad * 8);

  f32x4 oA[4], oB[4];
  {
    f32x4 z = {0.f, 0.f, 0.f, 0.f};
    #pragma unroll
    for (int dt = 0; dt < 4; ++dt) { oA[dt] = z; oB[dt] = z; }
  }
  float mA = -1e30f, lA = 0.f, mB = -1e30f, lB = 0.f;

  const u16* kbase = k + (size_t)bh * 131072;
  const u16* vbase = vt + (size_t)bh * 131072;
  const int r0 = tid >> 3, cc = tid & 7;
  // P-exchange source lanes: receiver (quad,ks) pulls W[2ks+hi] words from
  // lanes s0 (j=0..3) and s1 (j=4..7)  [verified R3]
  const int s0 = ((quad & 1) << 5) + l16, s1 = s0 + 16;
  const int hi = quad >> 1;

  // prologue: stage kt=0 into buffer 0
  {
    uint4 k0 = *(const uint4*)(kbase + (size_t)r0 * 64 + cc * 8);
    uint4 k1 = *(const uint4*)(kbase + (size_t)(r0 + 32) * 64 + cc * 8);
    uint4 v0 = *(const uint4*)(vbase + (size_t)r0 * 2048 + cc * 8);
    uint4 v1 = *(const uint4*)(vbase + (size_t)(r0 + 32) * 2048 + cc * 8);
    *(uint4*)(&Ks[0][r0 * 72 + cc * 8]) = k0;
    *(uint4*)(&Ks[0][(r0 + 32) * 72 + cc * 8]) = k1;
    *(uint4*)(&Vs[0][r0 * 72 + cc * 8]) = v0;
    *(uint4*)(&Vs[0][(r0 + 32) * 72 + cc * 8]) = v1;
  }
  __syncthreads();

  for (int kt = 0; kt <= qtA; ++kt) {
    const int p = kt & 1;
    const bool pre = (kt < qtA);
    uint4 kr0, kr1, vr0, vr1;
    if (pre) {  // issue next-tile loads early; consumed after compute
      const u16* kb = kbase + (size_t)(kt + 1) * 4096;
      const u16* vb = vbase + (kt + 1) * 64;
      kr0 = *(const uint4*)(kb + (size_t)r0 * 64 + cc * 8);
      kr1 = *(const uint4*)(kb + (size_t)(r0 + 32) * 64 + cc * 8);
      vr0 = *(const uint4*)(vb + (size_t)r0 * 2048 + cc * 8);
      vr1 = *(const uint4*)(vb + (size_t)(r0 + 32) * 2048 + cc * 8);
    }

    ATTN_SUB(p, qA0, qA1, oA, mA, lA, (kt == qtA))
    if (kt <= qtB) {
      ATTN_SUB(p, qB0, qB1, oB, mB, lB, (kt == qtB))
    }

    if (pre) {  // write next tile into the other buffer
      *(uint4*)(&Ks[p ^ 1][r0 * 72 + cc * 8]) = kr0;
      *(uint4*)(&Ks[p ^ 1][(r0 + 32) * 72 + cc * 8]) = kr1;
      *(uint4*)(&Vs[p ^ 1][r0 * 72 + cc * 8]) = vr0;
      *(uint4*)(&Vs[p ^ 1][(r0 + 32) * 72 + cc * 8]) = vr1;
    }
    __syncthreads();  // single barrier: orders buf[p^1] writes + buf[p] reads
  }

  ATTN_EPI(oA, lA, qtA)
  ATTN_EPI(oB, lB, qtB)
}

extern "C" void kernel_launch(void* const* d_in, const int* in_sizes, int n_in,
                              void* d_out, int out_size, void* d_ws, size_t ws_size,
                              hipStream_t stream) {
  const float* x  = (const float*)d_in[0];
  const float* Wq = (const float*)d_in[1];
  const float* bq = (const float*)d_in[2];
  const float* Wk = (const float*)d_in[3];
  const float* bk = (const float*)d_in[4];
  const float* Wv = (const float*)d_in[5];
  const float* bv = (const float*)d_in[6];
  const float* Wo = (const float*)d_in[7];
  const float* bo = (const float*)d_in[8];
  float* out = (float*)d_out;

  u16* ws  = (u16*)d_ws;
  u16* xb  = ws;                   // 8388608   x bf16 [8192][1024]
  u16* Wb  = ws + 8388608;         // 4x1048576 Wq|Wk|Wv|Wo bf16
  u16* qkv = ws + 12582912;        // 3x8388608 q|k (v region unused now)
  u16* vt  = ws + 37748736;        // 8388608   v^T [B,H,Dh,T] bf16
  u16* y   = ws + 46137344;        // 8388608   attn out [B,T,H,Dh] bf16

  k_convert<<<dim3(12288), dim3(256), 0, stream>>>(x, Wq, Wk, Wv, Wo, ws);
  k_gemm_qkv<<<dim3(384), dim3(512), 0, stream>>>(xb, Wb, bq, bk, bv, qkv, vt);
  k_attn<<<dim3(64, 16), dim3(256), 0, stream>>>(qkv, qkv + 8388608, vt, y);
  k_gemm_out<<<dim3(256), dim3(512), 0, stream>>>(y, Wb + 3 * 1048576, bo, out);
}

// Round 8
// 297.484 us; speedup vs baseline: 1.0805x; 1.0137x over previous
//
#include <hip/hip_runtime.h>

typedef __attribute__((ext_vector_type(8))) short short8;
typedef __attribute__((ext_vector_type(4))) float f32x4;
typedef unsigned short u16;
typedef unsigned int u32;

#define NH 16

#if __has_builtin(__builtin_amdgcn_exp2f)
#define EXP2(x) __builtin_amdgcn_exp2f(x)
#else
#define EXP2(x) exp2f(x)
#endif

__device__ __forceinline__ u32 f2bf(float f) {
  u32 u = __builtin_bit_cast(u32, f);
  return (u + 0x7fffu + ((u >> 16) & 1u)) >> 16;  // round-nearest-even bf16 bits
}

// v_cvt_pk_bf16_f32: two f32 -> packed bf16x2 (RNE), one instruction.
__device__ __forceinline__ u32 cvtpk(float lo, float hi) {
  u32 r;
  asm("v_cvt_pk_bf16_f32 %0, %1, %2" : "=v"(r) : "v"(lo), "v"(hi));
  return r;
}

// async global->LDS, 16B per lane. LDS dest is wave-uniform base + lane*16.
__device__ __forceinline__ void gload_lds16(const u16* g, u16* l) {
  __builtin_amdgcn_global_load_lds(
      (const __attribute__((address_space(1))) void*)g,
      (__attribute__((address_space(3))) void*)l, 16, 0, 0);
}

// ---------- convert x + Wq,Wk,Wv,Wo (fp32) -> bf16 into ws ----------
__global__ __launch_bounds__(256) void k_convert(
    const float* __restrict__ x, const float* __restrict__ wq,
    const float* __restrict__ wk, const float* __restrict__ wv,
    const float* __restrict__ wo, u16* __restrict__ dst) {
  int i = blockIdx.x * 256 + threadIdx.x;
  size_t e = (size_t)i * 4;
  const float* s; size_t off;
  if (e < 8388608ull)       { s = x;  off = e; }
  else if (e < 9437184ull)  { s = wq; off = e - 8388608ull; }
  else if (e < 10485760ull) { s = wk; off = e - 9437184ull; }
  else if (e < 11534336ull) { s = wv; off = e - 10485760ull; }
  else                      { s = wo; off = e - 11534336ull; }
  float4 d = *(const float4*)(s + off);
  uint2 o;
  o.x = cvtpk(d.x, d.y);
  o.y = cvtpk(d.z, d.w);
  *(uint2*)(dst + e) = o;
}

// ---------- parameterized 8-wave GEMM core (T3+T4): C = A * B^T ----------
// 512 threads = 8 waves (2M x 4N). BM = MT*32, BN = NT*64, BK = 64, K=1024.
// True dbuf LDS. Staging via gload_lds16 with constant-per-lane granule XOR
// swizzle (store col g^(row&7) via pre-swizzled source; read col
// (ks*4+quad)^(l16&7)). T4 counted vmcnt: after issuing tile t+1's NLD
// loads, wait vmcnt(NLD) -> only tile t's loads drain; t+1's stay in flight
// across all MFMA phases. Raw s_barrier only (no __syncthreads drain).
#define GPHASE(MH, NH_, LA, LB)                                                \
  if (LA) {                                                                    \
    _Pragma("unroll")                                                          \
    for (int mt = 0; mt < 4; ++mt)                                             \
      _Pragma("unroll")                                                        \
      for (int ks = 0; ks < 2; ++ks)                                           \
        af[mt][ks] = *(const short8*)(Ab +                                     \
            (wr * MT * 16 + ((MH) * 4 + mt) * 16 + l16) * 64 +                 \
            ((ks * 4 + quad) ^ swz) * 8);                                      \
  }                                                                            \
  if (LB) {                                                                    \
    _Pragma("unroll")                                                          \
    for (int nt = 0; nt < NH2; ++nt)                                           \
      _Pragma("unroll")                                                        \
      for (int ks = 0; ks < 2; ++ks)                                           \
        bfr[nt][ks] = *(const short8*)(Bb +                                    \
            (wn * NT * 16 + ((NH_) * NH2 + nt) * 16 + l16) * 64 +              \
            ((ks * 4 + quad) ^ swz) * 8);                                      \
  }                                                                            \
  __builtin_amdgcn_s_barrier();                                                \
  __builtin_amdgcn_s_setprio(1);                                               \
  _Pragma("unroll")                                                            \
  for (int mt = 0; mt < 4; ++mt)                                               \
    _Pragma("unroll")                                                          \
    for (int nt = 0; nt < NH2; ++nt)                                           \
      _Pragma("unroll")                                                        \
      for (int ks = 0; ks < 2; ++ks)                                           \
        acc[(MH) * 4 + mt][(NH_) * NH2 + nt] =                                 \
            __builtin_amdgcn_mfma_f32_16x16x32_bf16(                           \
                af[mt][ks], bfr[nt][ks], acc[(MH) * 4 + mt][(NH_) * NH2 + nt], \
                0, 0, 0);                                                      \
  __builtin_amdgcn_s_setprio(0);                                               \
  __builtin_amdgcn_s_barrier();                                                \
  __builtin_amdgcn_sched_barrier(0);

#define STAGE_T(T, PB)                                                         \
  {                                                                            \
    const u16* aT = aTh + (T) * 64;                                            \
    const u16* bT = bTh + (T) * 64;                                            \
    u16* aD = &As[PB][0] + dbase;                                              \
    u16* bD = &Bs[PB][0] + dbase;                                              \
    _Pragma("unroll")                                                          \
    for (int j = 0; j < NLA; ++j) gload_lds16(aT + j * 65536, aD + j * 4096);  \
    _Pragma("unroll")                                                          \
    for (int j = 0; j < NLB; ++j) gload_lds16(bT + j * 65536, bD + j * 4096);  \
  }

template <int MT, int NT>
__device__ __forceinline__ void gemm_core(const u16* __restrict__ Aptr,
                                          const u16* __restrict__ Bptr,
                                          int m0, int n0,
                                          f32x4 (&acc)[MT][NT]) {
  constexpr int NLA = MT / 2;   // A gload_lds per thread per K-tile
  constexpr int NLB = NT;       // B gload_lds per thread per K-tile
  constexpr int NLD = NLA + NLB;
  constexpr int NH2 = NT / 2;
  __shared__ u16 As[2][MT * 32 * 64];
  __shared__ u16 Bs[2][NT * 64 * 64];
  const int tid = threadIdx.x;
  const int wave = tid >> 6, lane = tid & 63;
  const int quad = lane >> 4, l16 = lane & 15;
  const int wr = wave >> 2, wn = wave & 3;
  const int swz = l16 & 7;
  const int srow = tid >> 3;
  const int srcg = (tid & 7) ^ (srow & 7);
  const u16* aTh = Aptr + (size_t)(m0 + srow) * 1024 + srcg * 8;
  const u16* bTh = Bptr + (size_t)(n0 + srow) * 1024 + srcg * 8;
  const int dbase = wave * 512;

  {
    f32x4 z = {0.f, 0.f, 0.f, 0.f};
    #pragma unroll
    for (int a = 0; a < MT; ++a)
      #pragma unroll
      for (int b2 = 0; b2 < NT; ++b2) acc[a][b2] = z;
  }

  STAGE_T(0, 0)

  short8 af[4][2], bfr[NH2][2];
  for (int t = 0; t < 16; ++t) {
    const int p = t & 1;
    if (t < 15) {
      STAGE_T(t + 1, p ^ 1)
      if constexpr (NLD == 8)
        asm volatile("s_waitcnt vmcnt(8)" ::: "memory");
      else if constexpr (NLD == 6)
        asm volatile("s_waitcnt vmcnt(6)" ::: "memory");
      else if constexpr (NLD == 4)
        asm volatile("s_waitcnt vmcnt(4)" ::: "memory");
      else
        asm volatile("s_waitcnt vmcnt(0)" ::: "memory");
    } else {
      asm volatile("s_waitcnt vmcnt(0)" ::: "memory");
    }
    __builtin_amdgcn_s_barrier();
    __builtin_amdgcn_sched_barrier(0);
    const u16* Ab = &As[p][0];
    const u16* Bb = &Bs[p][0];
    if constexpr (MT == 8) {
      GPHASE(0, 0, true, true)
      GPHASE(0, 1, false, true)
      GPHASE(1, 1, true, false)
      GPHASE(1, 0, false, true)
    } else {
      GPHASE(0, 0, true, true)
      GPHASE(0, 1, false, true)
    }
  }
}

// ---------- QKV projection, 128x256 tiles (768 blocks = 3 exact waves),
// fused N=3072; V written directly transposed ----------
__global__ __launch_bounds__(512, 2) void k_gemm_qkv(
    const u16* __restrict__ A, const u16* __restrict__ W,
    const float* __restrict__ bq, const float* __restrict__ bk,
    const float* __restrict__ bv, u16* __restrict__ qkv,
    u16* __restrict__ vt) {
  const int bid = blockIdx.x;                  // 768 blocks
  const int xw = (bid & 7) * 96 + (bid >> 3);  // bijective XCD chunking
  const int mtile = xw / 12, ntile = xw % 12;  // same-mtile neighbors share A
  const int m0 = mtile * 128, n0 = ntile * 256;
  const int z = n0 >> 10;
  const float* bias = (z == 0) ? bq : (z == 1) ? bk : bv;
  u16* out = qkv + (size_t)z * 8388608;
  // q: fold 1/sqrt(64) AND log2(e) (attention softmax runs in exp2 domain)
  const float scl = (z == 0) ? 0.125f * 1.44269504088896340736f : 1.0f;
  f32x4 acc[4][4];
  gemm_core<4, 4>(A, W, m0, n0, acc);
  const int tid = threadIdx.x;
  const int wave = tid >> 6, lane = tid & 63;
  const int quad = lane >> 4, l16 = lane & 15;
  const int wr = wave >> 2, wn = wave & 3;
  if (z == 2) {
    // V -> vt [B,H,Dh,T] directly; r-loop spans 4 consecutive t -> uint2
    #pragma unroll
    for (int mt = 0; mt < 4; ++mt) {
      #pragma unroll
      for (int nt = 0; nt < 4; ++nt) {
        int nn = (n0 + wn * 64 + nt * 16 + l16) & 1023;
        float bn = bias[nn];
        int h = nn >> 6, d = nn & 63;
        int mbase = m0 + wr * 64 + mt * 16 + quad * 4;
        int b = mbase >> 11, tb = mbase & 2047;
        uint2 pk;
        pk.x = cvtpk(acc[mt][nt][0] + bn, acc[mt][nt][1] + bn);
        pk.y = cvtpk(acc[mt][nt][2] + bn, acc[mt][nt][3] + bn);
        *(uint2*)(vt + ((size_t)(b * NH + h) * 64 + d) * 2048 + tb) = pk;
      }
    }
  } else {
    #pragma unroll
    for (int mt = 0; mt < 4; ++mt) {
      #pragma unroll
      for (int nt = 0; nt < 4; ++nt) {
        int nn = (n0 + wn * 64 + nt * 16 + l16) & 1023;
        float bn = bias[nn];
        int h = nn >> 6, d = nn & 63;
        #pragma unroll
        for (int r = 0; r < 4; ++r) {
          int m = m0 + wr * 64 + mt * 16 + quad * 4 + r;
          int b = m >> 11, tt = m & 2047;
          float val = (acc[mt][nt][r] + bn) * scl;
          out[(((size_t)(b * NH + h) * 2048 + tt) << 6) + d] = (u16)f2bf(val);
        }
      }
    }
  }
}

// ---------- output projection: 256x128 tiles -> 256 blocks = 1/CU ----------
__global__ __launch_bounds__(512, 2) void k_gemm_out(
    const u16* __restrict__ A, const u16* __restrict__ Bw,
    const float* __restrict__ bias, float* __restrict__ out) {
  const int bid = blockIdx.x;                 // 256 blocks
  const int sw = (bid & 7) * 32 + (bid >> 3); // XCD chunking: same mtile/XCD
  const int mtile = sw >> 3, ntile = sw & 7;
  const int m0 = mtile * 256, n0 = ntile * 128;
  f32x4 acc[8][2];
  gemm_core<8, 2>(A, Bw, m0, n0, acc);
  const int tid = threadIdx.x;
  const int wave = tid >> 6, lane = tid & 63;
  const int quad = lane >> 4, l16 = lane & 15;
  const int wr = wave >> 2, wn = wave & 3;
  #pragma unroll
  for (int mt = 0; mt < 8; ++mt) {
    #pragma unroll
    for (int nt = 0; nt < 2; ++nt) {
      int n = n0 + wn * 32 + nt * 16 + l16;
      float bn = bias[n];
      #pragma unroll
      for (int r = 0; r < 4; ++r) {
        int m = m0 + wr * 128 + mt * 16 + quad * 4 + r;
        out[(size_t)m * 1024 + n] = acc[mt][nt][r] + bn;
      }
    }
  }
}

// ---------- flash attention (R4-verified structure): S^T orientation,
// paired q-tiles, in-register P exchange, dbuf K/V LDS (1 barrier/step),
// same-bh-per-XCD grid for L2 K/V residency. R7: v_cvt_pk_bf16_f32 for the
// P bf16 pack (78 VALU ops -> 8 per sub-step). ----------
#define ATTN_SUB(P, QF0, QF1, O, MI, LI, DIAG)                                 \
  {                                                                            \
    f32x4 st[4];                                                               \
    _Pragma("unroll")                                                          \
    for (int nt = 0; nt < 4; ++nt) {                                           \
      short8 kf0 = *(const short8*)(&Ks[P][(nt * 16 + l16) * 72 + quad * 8]);  \
      short8 kf1 = *(const short8*)(&Ks[P][(nt * 16 + l16) * 72 + 32 + quad * 8]); \
      f32x4 z4 = {0.f, 0.f, 0.f, 0.f};                                         \
      z4 = __builtin_amdgcn_mfma_f32_16x16x32_bf16(kf0, QF0, z4, 0, 0, 0);     \
      st[nt] = __builtin_amdgcn_mfma_f32_16x16x32_bf16(kf1, QF1, z4, 0, 0, 0); \
    }                                                                          \
    if (DIAG) {                                                                \
      int q_loc = wave * 16 + l16;                                             \
      _Pragma("unroll")                                                        \
      for (int nt = 0; nt < 4; ++nt) {                                         \
        _Pragma("unroll")                                                      \
        for (int r = 0; r < 4; ++r) {                                          \
          int k_loc = nt * 16 + quad * 4 + r;                                  \
          if (k_loc > q_loc) st[nt][r] = -1e30f;                               \
        }                                                                      \
      }                                                                        \
    }                                                                          \
    float mq[4];                                                               \
    _Pragma("unroll")                                                          \
    for (int nt = 0; nt < 4; ++nt)                                             \
      mq[nt] = fmaxf(fmaxf(st[nt][0], st[nt][1]), fmaxf(st[nt][2], st[nt][3]));\
    float mx = fmaxf(fmaxf(mq[0], mq[1]), fmaxf(mq[2], mq[3]));                \
    mx = fmaxf(mx, __shfl_xor(mx, 16, 64));                                    \
    mx = fmaxf(mx, __shfl_xor(mx, 32, 64));                                    \
    float mnew = fmaxf(MI, mx);                                                \
    float alpha = EXP2(MI - mnew);                                             \
    MI = mnew;                                                                 \
    LI *= alpha;                                                               \
    _Pragma("unroll")                                                          \
    for (int r = 0; r < 4; ++r) {                                              \
      float av = __shfl(alpha, quad * 4 + r, 16);                              \
      _Pragma("unroll")                                                        \
      for (int dt = 0; dt < 4; ++dt) O[dt][r] *= av;                           \
    }                                                                          \
    u32 Wx[4], Wy[4];                                                          \
    float sq[4];                                                               \
    _Pragma("unroll")                                                          \
    for (int nt = 0; nt < 4; ++nt) {                                           \
      float p0 = EXP2(st[nt][0] - mnew);                                       \
      float p1 = EXP2(st[nt][1] - mnew);                                       \
      float p2 = EXP2(st[nt][2] - mnew);                                       \
      float p3 = EXP2(st[nt][3] - mnew);                                       \
      sq[nt] = (p0 + p1) + (p2 + p3);                                          \
      Wx[nt] = cvtpk(p0, p1);                                                  \
      Wy[nt] = cvtpk(p2, p3);                                                  \
    }                                                                          \
    float sum = (sq[0] + sq[1]) + (sq[2] + sq[3]);                             \
    sum += __shfl_xor(sum, 16, 64);                                            \
    sum += __shfl_xor(sum, 32, 64);                                            \
    LI += sum;                                                                 \
    uint4 t0, t1;                                                              \
    {                                                                          \
      u32 e, f;                                                                \
      e = __shfl(Wx[0], s0, 64); f = __shfl(Wx[1], s0, 64); t0.x = hi ? f : e; \
      e = __shfl(Wy[0], s0, 64); f = __shfl(Wy[1], s0, 64); t0.y = hi ? f : e; \
      e = __shfl(Wx[0], s1, 64); f = __shfl(Wx[1], s1, 64); t0.z = hi ? f : e; \
      e = __shfl(Wy[0], s1, 64); f = __shfl(Wy[1], s1, 64); t0.w = hi ? f : e; \
      e = __shfl(Wx[2], s0, 64); f = __shfl(Wx[3], s0, 64); t1.x = hi ? f : e; \
      e = __shfl(Wy[2], s0, 64); f = __shfl(Wy[3], s0, 64); t1.y = hi ? f : e; \
      e = __shfl(Wx[2], s1, 64); f = __shfl(Wx[3], s1, 64); t1.z = hi ? f : e; \
      e = __shfl(Wy[2], s1, 64); f = __shfl(Wy[3], s1, 64); t1.w = hi ? f : e; \
    }                                                                          \
    short8 pf0 = __builtin_bit_cast(short8, t0);                               \
    short8 pf1 = __builtin_bit_cast(short8, t1);                               \
    _Pragma("unroll")                                                          \
    for (int dt = 0; dt < 4; ++dt) {                                           \
      short8 vf0 = *(const short8*)(&Vs[P][(dt * 16 + l16) * 72 + quad * 8]);  \
      short8 vf1 = *(const short8*)(&Vs[P][(dt * 16 + l16) * 72 + 32 + quad * 8]); \
      O[dt] = __builtin_amdgcn_mfma_f32_16x16x32_bf16(pf0, vf0, O[dt], 0, 0, 0); \
      O[dt] = __builtin_amdgcn_mfma_f32_16x16x32_bf16(pf1, vf1, O[dt], 0, 0, 0); \
    }                                                                          \
  }

#define ATTN_EPI(O, LI, QT)                                                    \
  _Pragma("unroll")                                                            \
  for (int r = 0; r < 4; ++r) {                                                \
    float lv = __shfl(LI, quad * 4 + r, 16);                                   \
    float inv = 1.0f / lv;                                                     \
    int t = (QT) * 64 + wave * 16 + quad * 4 + r;                              \
    _Pragma("unroll")                                                          \
    for (int dt = 0; dt < 4; ++dt) {                                           \
      int d = dt * 16 + l16;                                                   \
      y[(((size_t)b * 2048 + t) * NH + h) * 64 + d] = (u16)f2bf(O[dt][r] * inv); \
    }                                                                          \
  }

__global__ __launch_bounds__(256, 4) void k_attn(
    const u16* __restrict__ q, const u16* __restrict__ k,
    const u16* __restrict__ vt, u16* __restrict__ y) {
  const int tid = threadIdx.x;
  const int wave = tid >> 6, lane = tid & 63;
  const int quad = lane >> 4, l16 = lane & 15;
  const int bh = blockIdx.x, bx = blockIdx.y;  // grid (64,16): id%8 = bh%8
  const int qtB = bx, qtA = 31 - bx;           // qtB in 0..15, qtA in 16..31
  const int b = bh >> 4, h = bh & 15;

  __shared__ u16 Ks[2][64 * 72];
  __shared__ u16 Vs[2][64 * 72];               // [d][kidx]

  const u16* qbA = q + ((size_t)bh * 2048 + qtA * 64 + wave * 16 + l16) * 64;
  short8 qA0 = *(const short8*)(qbA + quad * 8);
  short8 qA1 = *(const short8*)(qbA + 32 + quad * 8);
  const u16* qbB = q + ((size_t)bh * 2048 + qtB * 64 + wave * 16 + l16) * 64;
  short8 qB0 = *(const short8*)(qbB + quad * 8);
  short8 qB1 = *(const short8*)(qbB + 32 + quad * 8);

  f32x4 oA[4], oB[4];
  {
    f32x4 z = {0.f, 0.f, 0.f, 0.f};
    #pragma unroll
    for (int dt = 0; dt < 4; ++dt) { oA[dt] = z; oB[dt] = z; }
  }
  float mA = -1e30f, lA = 0.f, mB = -1e30f, lB = 0.f;

  const u16* kbase = k + (size_t)bh * 131072;
  const u16* vbase = vt + (size_t)bh * 131072;
  const int r0 = tid >> 3, cc = tid & 7;
  // P-exchange source lanes: receiver (quad,ks) pulls W[2ks+hi] words from
  // lanes s0 (j=0..3) and s1 (j=4..7)  [verified R3]
  const int s0 = ((quad & 1) << 5) + l16, s1 = s0 + 16;
  const int hi = quad >> 1;

  // prologue: stage kt=0 into buffer 0
  {
    uint4 k0 = *(const uint4*)(kbase + (size_t)r0 * 64 + cc * 8);
    uint4 k1 = *(const uint4*)(kbase + (size_t)(r0 + 32) * 64 + cc * 8);
    uint4 v0 = *(const uint4*)(vbase + (size_t)r0 * 2048 + cc * 8);
    uint4 v1 = *(const uint4*)(vbase + (size_t)(r0 + 32) * 2048 + cc * 8);
    *(uint4*)(&Ks[0][r0 * 72 + cc * 8]) = k0;
    *(uint4*)(&Ks[0][(r0 + 32) * 72 + cc * 8]) = k1;
    *(uint4*)(&Vs[0][r0 * 72 + cc * 8]) = v0;
    *(uint4*)(&Vs[0][(r0 + 32) * 72 + cc * 8]) = v1;
  }
  __syncthreads();

  for (int kt = 0; kt <= qtA; ++kt) {
    const int p = kt & 1;
    const bool pre = (kt < qtA);
    uint4 kr0, kr1, vr0, vr1;
    if (pre) {  // issue next-tile loads early; consumed after compute
      const u16* kb = kbase + (size_t)(kt + 1) * 4096;
      const u16* vb = vbase + (kt + 1) * 64;
      kr0 = *(const uint4*)(kb + (size_t)r0 * 64 + cc * 8);
      kr1 = *(const uint4*)(kb + (size_t)(r0 + 32) * 64 + cc * 8);
      vr0 = *(const uint4*)(vb + (size_t)r0 * 2048 + cc * 8);
      vr1 = *(const uint4*)(vb + (size_t)(r0 + 32) * 2048 + cc * 8);
    }

    ATTN_SUB(p, qA0, qA1, oA, mA, lA, (kt == qtA))
    if (kt <= qtB) {
      ATTN_SUB(p, qB0, qB1, oB, mB, lB, (kt == qtB))
    }

    if (pre) {  // write next tile into the other buffer
      *(uint4*)(&Ks[p ^ 1][r0 * 72 + cc * 8]) = kr0;
      *(uint4*)(&Ks[p ^ 1][(r0 + 32) * 72 + cc * 8]) = kr1;
      *(uint4*)(&Vs[p ^ 1][r0 * 72 + cc * 8]) = vr0;
      *(uint4*)(&Vs[p ^ 1][(r0 + 32) * 72 + cc * 8]) = vr1;
    }
    __syncthreads();  // single barrier: orders buf[p^1] writes + buf[p] reads
  }

  ATTN_EPI(oA, lA, qtA)
  ATTN_EPI(oB, lB, qtB)
}

extern "C" void kernel_launch(void* const* d_in, const int* in_sizes, int n_in,
                              void* d_out, int out_size, void* d_ws, size_t ws_size,
                              hipStream_t stream) {
  const float* x  = (const float*)d_in[0];
  const float* Wq = (const float*)d_in[1];
  const float* bq = (const float*)d_in[2];
  const float* Wk = (const float*)d_in[3];
  const float* bk = (const float*)d_in[4];
  const float* Wv = (const float*)d_in[5];
  const float* bv = (const float*)d_in[6];
  const float* Wo = (const float*)d_in[7];
  const float* bo = (const float*)d_in[8];
  float* out = (float*)d_out;

  u16* ws  = (u16*)d_ws;
  u16* xb  = ws;                   // 8388608   x bf16 [8192][1024]
  u16* Wb  = ws + 8388608;         // 4x1048576 Wq|Wk|Wv|Wo bf16
  u16* qkv = ws + 12582912;        // 3x8388608 q|k (v region unused now)
  u16* vt  = ws + 37748736;        // 8388608   v^T [B,H,Dh,T] bf16
  u16* y   = ws + 46137344;        // 8388608   attn out [B,T,H,Dh] bf16

  k_convert<<<dim3(12288), dim3(256), 0, stream>>>(x, Wq, Wk, Wv, Wo, ws);
  k_gemm_qkv<<<dim3(768), dim3(512), 0, stream>>>(xb, Wb, bq, bk, bv, qkv, vt);
  k_attn<<<dim3(64, 16), dim3(256), 0, stream>>>(qkv, qkv + 8388608, vt, y);
  k_gemm_out<<<dim3(256), dim3(512), 0, stream>>>(y, Wb + 3 * 1048576, bo, out);
}